// Round 10
// baseline (268.435 us; speedup 1.0000x reference)
//
#include <hip/hip_runtime.h>
#include <hip/hip_bf16.h>

// GCN 2-layer forward. Pipeline (5 kernels):
//   prep          : zero bucket cursors + W1,W2 -> bf16 transposed (Wt[n][k])
//   bin_edges     : edges -> bucket-strided (src,dst) pairs
//   build_csr     : per-bucket LDS histogram/prefix -> dinv, rbeg/rend, csr,
//                   AND u = bf16(z * dinv[:,None])
//   agg_gemm12    : per 32-node tile: agg1 = u_d + sum u_s  (gather -> LDS),
//                   x1 = relu(dinv*(agg1@W1)+b1) (LDS), hs2 = bf16(dinv*(x1@W2))
//                   — both GEMMs on MFMA, B-fragments straight from global (L1)
//   aggregate POST: out_d = dinv_d*(hs2_d + sum hs2_s) + b2   (fp32 out)

#define WAVE 64
#define BSHIFT 8
#define NPB 256              // nodes per bucket
#define CAP 5120             // max edges per bucket (mean 4096, +16 sigma)
#define CH 4096              // edges per WG in bin_edges
#define NBMAX 512

typedef __attribute__((ext_vector_type(8))) short bf16x8;
typedef __attribute__((ext_vector_type(4))) float f32x4;

__device__ inline float bf16_to_f32(unsigned short h) {
    return __uint_as_float(((unsigned int)h) << 16);
}
__device__ inline unsigned short f32_to_bf16(float f) {
    unsigned int x = __float_as_uint(f);
    return (unsigned short)((x + 0x7FFFu + ((x >> 16) & 1u)) >> 16);   // RNE
}

// ---------------- prep: zero cursors + W -> bf16 transposed ----------------
__global__ void prep(const float* __restrict__ W1, const float* __restrict__ W2,
                     unsigned short* __restrict__ W1t, unsigned short* __restrict__ W2t,
                     int* __restrict__ bcursor, int NB)
{
    int i = blockIdx.x * blockDim.x + threadIdx.x;
    if (i < NB) bcursor[i] = 0;
    if (i < 128 * 64) {          // W1t[n][k] = W1[k][n]  (W1 is [64][128])
        int n = i >> 6, k = i & 63;
        W1t[i] = f32_to_bf16(W1[k * 128 + n]);
    }
    if (i < 64 * 128) {          // W2t[n][k] = W2[k][n]  (W2 is [128][64])
        int n = i >> 7, k = i & 127;
        W2t[i] = f32_to_bf16(W2[k * 64 + n]);
    }
}

// ---------------- bin_edges: scatter edges into bucket-strided ebuf ---------
__global__ __launch_bounds__(256) void bin_edges(
        const int* __restrict__ src, const int* __restrict__ dst,
        int* __restrict__ bcursor, int2* __restrict__ ebuf, int E, int NB)
{
    __shared__ int hist[NBMAX];
    __shared__ int cur[NBMAX];
    const int t  = threadIdx.x;
    const int e0 = blockIdx.x * CH;

    for (int b = t; b < NB; b += 256) hist[b] = 0;
    __syncthreads();

#pragma unroll
    for (int j = 0; j < CH / 256; ++j) {
        int e = e0 + j * 256 + t;
        if (e < E) atomicAdd(&hist[dst[e] >> BSHIFT], 1);
    }
    __syncthreads();

    for (int b = t; b < NB; b += 256) {
        int c = hist[b];
        cur[b] = (c > 0) ? atomicAdd(&bcursor[b], c) : 0;
    }
    __syncthreads();

#pragma unroll
    for (int j = 0; j < CH / 256; ++j) {
        int e = e0 + j * 256 + t;
        if (e < E) {
            int s = src[e], d = dst[e];
            int b = d >> BSHIFT;
            int pos = atomicAdd(&cur[b], 1);
            ebuf[(size_t)b * CAP + pos] = make_int2(s, d);
        }
    }
}

// ---------------- build_csr + fused u = bf16(z*dinv) ----------------
__global__ __launch_bounds__(256) void build_csr(
        const int2* __restrict__ ebuf, const int* __restrict__ bcursor,
        const float* __restrict__ z, float* __restrict__ dinv,
        int* __restrict__ rbeg, int* __restrict__ rend,
        int* __restrict__ csr, unsigned short* __restrict__ u, int N)
{
    __shared__ int   h[NPB];
    __shared__ int   tmp[NPB];
    __shared__ float sdv[NPB];
    const int t   = threadIdx.x;
    const int b   = blockIdx.x;
    const int n0  = b << BSHIFT;
    const int cnt = bcursor[b];
    const size_t base = (size_t)b * CAP;

    h[t] = 0;
    __syncthreads();

    for (int i = t; i < cnt; i += 256)
        atomicAdd(&h[ebuf[base + i].y - n0], 1);
    __syncthreads();

    int deg = h[t];
    tmp[t] = deg;
    __syncthreads();
    for (int off = 1; off < 256; off <<= 1) {
        int x = (t >= off) ? tmp[t - off] : 0;
        __syncthreads();
        tmp[t] += x;
        __syncthreads();
    }
    int st = tmp[t] - deg;

    int node = n0 + t;
    float di = rsqrtf((float)deg + 1.0f);
    sdv[t] = di;
    if (node < N) {
        dinv[node] = di;
        rbeg[node] = (int)base + st;
        rend[node] = (int)base + st + deg;
    }
    h[t] = st;
    __syncthreads();   // covers h-cursor reset and sdv visibility

    for (int i = t; i < cnt; i += 256) {
        int2 e = ebuf[base + i];
        int p = atomicAdd(&h[e.y - n0], 1);
        csr[base + p] = e.x;
    }

    // fused scale: u rows for this bucket (16 threads per row, float4 reads)
    const int nloc = (N - n0 < NPB) ? (N - n0) : NPB;
    for (int i = t; i < nloc * 16; i += 256) {
        int r = i >> 4, kq = i & 15;
        float d2 = sdv[r];
        float4 v = ((const float4*)(z + (size_t)(n0 + r) * 64))[kq];
        ushort4 o;
        o.x = f32_to_bf16(v.x * d2);
        o.y = f32_to_bf16(v.y * d2);
        o.z = f32_to_bf16(v.z * d2);
        o.w = f32_to_bf16(v.w * d2);
        ((ushort4*)(u + (size_t)(n0 + r) * 64))[kq] = o;
    }
}

// ---------------- aggregate POST (F=64, bf16 rows), one wave per node ------
__global__ __launch_bounds__(256) void aggregate64_post(
        const unsigned short* __restrict__ hs, const int* __restrict__ rbeg,
        const int* __restrict__ rend, const int* __restrict__ csr,
        const float* __restrict__ dinv, const float* __restrict__ b,
        float* __restrict__ out, int N)
{
    int node = (int)((blockIdx.x * (size_t)blockDim.x + threadIdx.x) >> 6);
    int lane = threadIdx.x & 63;
    if (node >= N) return;
    node = __builtin_amdgcn_readfirstlane(node);   // wave-uniform -> scalar loads

    const int beg = rbeg[node];
    const int end = rend[node];

    float acc = bf16_to_f32(hs[(size_t)node * 64 + lane]);   // self-loop term

    int e = beg;
    for (; e + 16 <= end; e += 16) {
        int s[16];
#pragma unroll
        for (int j = 0; j < 16; ++j) s[j] = csr[e + j];
        float v[16];
#pragma unroll
        for (int j = 0; j < 16; ++j) v[j] = bf16_to_f32(hs[(size_t)s[j] * 64 + lane]);
        float t0 = ((v[0] + v[1]) + (v[2] + v[3])) + ((v[4] + v[5]) + (v[6] + v[7]));
        float t1 = ((v[8] + v[9]) + (v[10] + v[11])) + ((v[12] + v[13]) + (v[14] + v[15]));
        acc += t0 + t1;
    }
    for (; e + 4 <= end; e += 4) {
        int s0 = csr[e+0], s1 = csr[e+1], s2 = csr[e+2], s3 = csr[e+3];
        float v0 = bf16_to_f32(hs[(size_t)s0 * 64 + lane]);
        float v1 = bf16_to_f32(hs[(size_t)s1 * 64 + lane]);
        float v2 = bf16_to_f32(hs[(size_t)s2 * 64 + lane]);
        float v3 = bf16_to_f32(hs[(size_t)s3 * 64 + lane]);
        acc += (v0 + v1) + (v2 + v3);
    }
    for (; e < end; ++e)
        acc += bf16_to_f32(hs[(size_t)csr[e] * 64 + lane]);

    out[(size_t)node * 64 + lane] = dinv[node] * acc + b[lane];
}

// ---------------- fused aggregate-PRE + dual MFMA GEMM ----------------
// Per 32-node tile: each wave gathers 8 nodes (agg1 rows -> LDS bf16 A-tile),
// then phase 1 (x1 -> LDS) and phase 2 (hs2 -> global) on MFMA.
// B-fragments are read straight from global W1t/W2t (16 KB each, L1-resident).
// mfma_f32_16x16x32_bf16 layouts (HW-verified R9):
//   A: lane holds A[m=lane&15][k=(lane>>4)*8+j]; B from Wt[n][k] rows;
//   C/D: col=lane&15, row=(lane>>4)*4+reg.
#define TILE 32
#define A_ST   72          // ushorts; 144 B row stride (16B-aligned, padded)
#define X1_ST  136         // ushorts; 272 B row stride (16B-aligned, padded)

__global__ __launch_bounds__(256) void agg_gemm12(
        const unsigned short* __restrict__ u,      // bf16 [N][64]
        const int* __restrict__ rbeg, const int* __restrict__ rend,
        const int* __restrict__ csr, const float* __restrict__ dinv,
        const unsigned short* __restrict__ W1t,    // bf16 [128][64] (n-major)
        const float* __restrict__ b1,              // [128]
        const unsigned short* __restrict__ W2t,    // bf16 [64][128] (n-major)
        unsigned short* __restrict__ hs2, int N)
{
    __shared__ unsigned short sA[TILE * A_ST];
    __shared__ unsigned short sX[TILE * X1_ST];
    __shared__ float sdv[TILE];

    const int tid  = threadIdx.x;
    const int row0 = blockIdx.x * TILE;
    const int lane = tid & 63;
    const int wv   = tid >> 6;        // wave 0..3
    const int l16  = lane & 15;
    const int quad = lane >> 4;       // 0..3

    // ---- gather phase: wave wv aggregates nodes row0 + wv*8 .. +7 ----
    for (int i = 0; i < 8; ++i) {
        const int lr   = wv * 8 + i;
        const int node = row0 + lr;            // wave-uniform
        float acc = 0.0f;
        float di  = 0.0f;
        if (node < N) {
            di  = dinv[node];
            acc = bf16_to_f32(u[(size_t)node * 64 + lane]);   // self-loop
            const int beg = rbeg[node];
            const int end = rend[node];
            int e = beg;
            for (; e + 16 <= end; e += 16) {
                int s[16];
#pragma unroll
                for (int j = 0; j < 16; ++j) s[j] = csr[e + j];
                float v[16];
#pragma unroll
                for (int j = 0; j < 16; ++j) v[j] = bf16_to_f32(u[(size_t)s[j] * 64 + lane]);
                float t0 = ((v[0] + v[1]) + (v[2] + v[3])) + ((v[4] + v[5]) + (v[6] + v[7]));
                float t1 = ((v[8] + v[9]) + (v[10] + v[11])) + ((v[12] + v[13]) + (v[14] + v[15]));
                acc += t0 + t1;
            }
            for (; e + 4 <= end; e += 4) {
                int s0 = csr[e+0], s1 = csr[e+1], s2 = csr[e+2], s3 = csr[e+3];
                float v0 = bf16_to_f32(u[(size_t)s0 * 64 + lane]);
                float v1 = bf16_to_f32(u[(size_t)s1 * 64 + lane]);
                float v2 = bf16_to_f32(u[(size_t)s2 * 64 + lane]);
                float v3 = bf16_to_f32(u[(size_t)s3 * 64 + lane]);
                acc += (v0 + v1) + (v2 + v3);
            }
            for (; e < end; ++e)
                acc += bf16_to_f32(u[(size_t)csr[e] * 64 + lane]);
        }
        sA[lr * A_ST + lane] = f32_to_bf16(acc);
        if (lane == 0) sdv[lr] = di;
    }
    __syncthreads();

    // ---- phase 1: x1 = relu(dinv*(agg1@W1)+b1) -> sX (32x128, 16 tiles) ----
    {
        const int mt  = wv & 1;
        const int ntb = (wv >> 1) * 4;
        f32x4 acc[4];
#pragma unroll
        for (int t = 0; t < 4; ++t) acc[t] = (f32x4)0.0f;

#pragma unroll
        for (int k0 = 0; k0 < 64; k0 += 32) {
            bf16x8 af = *(const bf16x8*)&sA[(mt * 16 + l16) * A_ST + k0 + quad * 8];
#pragma unroll
            for (int t = 0; t < 4; ++t) {
                int ng = (ntb + t) * 16 + l16;
                bf16x8 bf = *(const bf16x8*)&W1t[ng * 64 + k0 + quad * 8];
                acc[t] = __builtin_amdgcn_mfma_f32_16x16x32_bf16(af, bf, acc[t], 0, 0, 0);
            }
        }

#pragma unroll
        for (int t = 0; t < 4; ++t) {
            int col = (ntb + t) * 16 + l16;
            float bb = b1[col];
#pragma unroll
            for (int r = 0; r < 4; ++r) {
                int lr = mt * 16 + quad * 4 + r;
                float o = fmaxf(acc[t][r] * sdv[lr] + bb, 0.0f);
                sX[lr * X1_ST + col] = f32_to_bf16(o);
            }
        }
    }
    __syncthreads();

    // ---- phase 2: hs2 = bf16(dinv*(x1@W2)) (32x64, 8 tiles) ----
    {
        const int mt  = wv & 1;
        const int ntb = (wv >> 1) * 2;
        f32x4 acc[2];
#pragma unroll
        for (int t = 0; t < 2; ++t) acc[t] = (f32x4)0.0f;

#pragma unroll
        for (int k0 = 0; k0 < 128; k0 += 32) {
            bf16x8 af = *(const bf16x8*)&sX[(mt * 16 + l16) * X1_ST + k0 + quad * 8];
#pragma unroll
            for (int t = 0; t < 2; ++t) {
                int ng = (ntb + t) * 16 + l16;
                bf16x8 bf = *(const bf16x8*)&W2t[ng * 128 + k0 + quad * 8];
                acc[t] = __builtin_amdgcn_mfma_f32_16x16x32_bf16(af, bf, acc[t], 0, 0, 0);
            }
        }

#pragma unroll
        for (int t = 0; t < 2; ++t) {
            int col = (ntb + t) * 16 + l16;
#pragma unroll
            for (int r = 0; r < 4; ++r) {
                int lr = mt * 16 + quad * 4 + r;
                int gr = row0 + lr;
                if (gr < N)
                    hs2[(size_t)gr * 64 + col] = f32_to_bf16(acc[t][r] * sdv[lr]);
            }
        }
    }
}

static inline size_t align_up(size_t x, size_t a) { return (x + a - 1) / a * a; }

extern "C" void kernel_launch(void* const* d_in, const int* in_sizes, int n_in,
                              void* d_out, int out_size, void* d_ws, size_t ws_size,
                              hipStream_t stream) {
    const float* z    = (const float*)d_in[0];   // [N,64]
    const int*   eidx = (const int*)d_in[1];     // [2,E]: src row then dst row
    const float* W1   = (const float*)d_in[2];   // [64,128]
    const float* b1   = (const float*)d_in[3];   // [128]
    const float* W2   = (const float*)d_in[4];   // [128,64]
    const float* b2   = (const float*)d_in[5];   // [64]
    float* out = (float*)d_out;                  // [N,64]

    const int N = in_sizes[0] / 64;
    const int E = in_sizes[1] / 2;
    const int* src = eidx;
    const int* dst = eidx + E;
    const int NB = (N + NPB - 1) >> BSHIFT;      // 391 for N=100000

    // Workspace: small arrays | W1t | W2t | csr | bufA | bufB | bufC
    // u (bf16) in bufA; hs2 (bf16) in bufB (MUST NOT alias u: agg_gemm12
    // writes hs2 while other WGs still gather from u); ebuf aliases bufC.
    char* ws = (char*)d_ws;
    size_t off = 0;
    float* dinv    = (float*)(ws + off); off = align_up(off + (size_t)N * 4, 512);
    int*   rbeg    = (int*)  (ws + off); off = align_up(off + (size_t)N * 4, 512);
    int*   rend    = (int*)  (ws + off); off = align_up(off + (size_t)N * 4, 512);
    int*   bcursor = (int*)  (ws + off); off = align_up(off + (size_t)NBMAX * 4, 512);
    unsigned short* W1t = (unsigned short*)(ws + off); off = align_up(off + 8192 * 2, 512);
    unsigned short* W2t = (unsigned short*)(ws + off); off = align_up(off + 8192 * 2, 512);
    int*   csr     = (int*)  (ws + off); off = align_up(off + (size_t)NB * CAP * 4, 512);
    float* bufA    = (float*)(ws + off); off = align_up(off + (size_t)N * 64 * 4, 512);
    float* bufB    = (float*)(ws + off); off = align_up(off + (size_t)N * 64 * 4, 512);
    float* bufC    = (float*)(ws + off); off = align_up(off + (size_t)N * 128 * 4, 512);
    int2*  ebuf    = (int2*)bufC;
    (void)ws_size;

    unsigned short* u   = (unsigned short*)bufA;   // bf16 z*dinv
    unsigned short* hs2 = (unsigned short*)bufB;   // bf16 layer-2 pre-aggregate

    // ---- prep (cursor zero + W transpose/convert) ----
    prep<<<32, 256, 0, stream>>>(W1, W2, W1t, W2t, bcursor, NB);

    // ---- CSR build (+ fused dinv & u-scale) ----
    bin_edges<<<(E + CH - 1) / CH, 256, 0, stream>>>(src, dst, bcursor, ebuf, E, NB);
    build_csr<<<NB, 256, 0, stream>>>(ebuf, bcursor, z, dinv, rbeg, rend, csr, u, N);

    // ---- fused aggregate-PRE + dual MFMA GEMM ----
    agg_gemm12<<<(N + TILE - 1) / TILE, 256, 0, stream>>>(
        u, rbeg, rend, csr, dinv, W1t, b1, W2t, hs2, N);

    // ---- layer 2 aggregate (post-GEMM, bf16 gather, fp32 out) ----
    aggregate64_post<<<(N + 3) / 4, 256, 0, stream>>>(hs2, rbeg, rend, csr, dinv, b2, out, N);
}